// Round 7
// baseline (995.348 us; speedup 1.0000x reference)
//
#include <hip/hip_runtime.h>
#include <hip/hip_bf16.h>
#include <stdint.h>

#define NTOT 131072
#define NSEG 16
#define EPSV 1e-5f

typedef __attribute__((ext_vector_type(8))) short bf16x8;
typedef __attribute__((ext_vector_type(4))) float f32x4;

struct Args {
  const float* x; const int* npts;
  const float *W1,*b1,*g1,*be1,*m1,*v1;
  const float *W2,*b2,*g2,*be2,*m2,*v2;
  const float *W3,*b3,*g3,*be3,*m3,*v3;
  const float *W4,*b4,*g4,*be4,*m4,*v4;
  int* offs;
  float *a1,*c1,*a2,*c2,*a3,*c3,*a4,*c4;
  unsigned int *gkeys,*vkeys;
  unsigned short *w2b;
  unsigned short *w3p;     // [8 ks][4 kg][512 cout][8]   (f-part of W3, k=256..512)
  unsigned short *w4p;     // [16 ks][4 kg][1024 cout][8]
  unsigned short *fbufp;   // [2048 tiles][32 kg][64 pt][8]
  unsigned short *h3p;     // [2048 tiles][64 kg][64 pt][8]
  float* cseg;             // [16][512] = W3[:, :256] @ gs(seg)
  float* out;
};

__device__ inline unsigned int f2key(float f){ unsigned u=__float_as_uint(f); return (u&0x80000000u)? ~u : (u|0x80000000u); }
__device__ inline float key2f(unsigned k){ unsigned u=(k&0x80000000u)? (k^0x80000000u) : ~k; return __uint_as_float(u); }
__device__ inline unsigned short f2bf(float f){ __hip_bfloat16 h=__float2bfloat16(f); return *(unsigned short*)&h; }

__device__ inline void gl16(const void* g, void* l){
  __builtin_amdgcn_global_load_lds((const __attribute__((address_space(1))) unsigned int*)g,
                                   (__attribute__((address_space(3))) unsigned int*)l, 16, 0, 0);
}

// ---------------- setup ----------------
__global__ void k_setup(Args A){
  int tid = threadIdx.x;
  if (tid==0){ int s=0; A.offs[0]=0; for (int i=0;i<NSEG;i++){ s+=A.npts[i]; A.offs[i+1]=s; } }
  for (int c=tid;c<128;c+=256){ float a=A.g1[c]*rsqrtf(A.v1[c]+EPSV); A.a1[c]=a; A.c1[c]=A.be1[c]+a*(A.b1[c]-A.m1[c]); }
  for (int c=tid;c<256;c+=256){ float a=A.g2[c]*rsqrtf(A.v2[c]+EPSV); A.a2[c]=a; A.c2[c]=A.be2[c]+a*(A.b2[c]-A.m2[c]); }
  for (int c=tid;c<512;c+=256){ float a=A.g3[c]*rsqrtf(A.v3[c]+EPSV); A.a3[c]=a; A.c3[c]=A.be3[c]+a*(A.b3[c]-A.m3[c]); }
  for (int c=tid;c<1024;c+=256){ float a=A.g4[c]*rsqrtf(A.v4[c]+EPSV); A.a4[c]=a; A.c4[c]=A.be4[c]+a*(A.b4[c]-A.m4[c]); }
  for (int i=tid;i<NSEG*256;i+=256)  A.gkeys[i]=0u;
  for (int i=tid;i<NSEG*1024;i+=256) A.vkeys[i]=0u;
}

// ---------------- weights fp32 -> bf16 (+ gl16-friendly packing for L3/L4) ----------------
__global__ void k_conv(Args A){
  const int n1=256*128;        // w2b
  const int n2=8*4*512*8;      // w3p = 131072
  const int n3=16*4*1024*8;    // w4p = 524288
  for (int i = blockIdx.x*256+threadIdx.x; i < n1+n2+n3; i += gridDim.x*256){
    if (i<n1) A.w2b[i]=f2bf(A.W2[i]);
    else if (i<n1+n2){
      int o=i-n1; int j=o&7, cout=(o>>3)&511, g=o>>12; int ks=g>>2, kg=g&3;
      A.w3p[o]=f2bf(A.W3[(size_t)cout*512 + 256 + ks*32+kg*8+j]);
    } else {
      int o=i-n1-n2; int j=o&7, cout=(o>>3)&1023, g=o>>13; int ks=g>>2, kg=g&3;
      A.w4p[o]=f2bf(A.W4[(size_t)cout*512 + ks*32+kg*8+j]);
    }
  }
}

// ---------------- L1 (VALU) + L2 (MFMA) + BN -> fbufp packed + gkeys ----------------
__global__ __launch_bounds__(256) void k_l12(Args A){
  __shared__ float w1s[384], a1s[128], c1s[128], a2s[256], c2s[256];
  __shared__ float xs[3][64];
  __shared__ int offs_s[NSEG+1], segp[64];
  __shared__ unsigned short hs[16*64*8];
  int tid=threadIdx.x, pt0=blockIdx.x*64;
  for (int i=tid;i<384;i+=256) w1s[i]=A.W1[i];
  if (tid<128){ a1s[tid]=A.a1[tid]; c1s[tid]=A.c1[tid]; }
  a2s[tid]=A.a2[tid]; c2s[tid]=A.c2[tid];
  if (tid<=NSEG) offs_s[tid]=A.offs[tid];
  if (tid<64){ xs[0][tid]=A.x[pt0+tid]; xs[1][tid]=A.x[NTOT+pt0+tid]; xs[2][tid]=A.x[2*NTOT+pt0+tid]; }
  __syncthreads();
  if (tid<64){ int gp=pt0+tid, s=0; while (gp>=offs_s[s+1]) s++; segp[tid]=s; }
  for (int pair=tid; pair<1024; pair+=256){
    int pt=pair&63, kc=pair>>6;
    float x0=xs[0][pt], x1=xs[1][pt], x2=xs[2][pt];
    unsigned short us[8];
    #pragma unroll
    for (int j=0;j<8;j++){
      int cin=kc*8+j;
      float v = fmaf(w1s[cin*3],x0, fmaf(w1s[cin*3+1],x1, w1s[cin*3+2]*x2));
      v = fmaxf(fmaf(a1s[cin],v,c1s[cin]), 0.f);
      us[j]=f2bf(v);
    }
    uint4 pk;
    pk.x=(unsigned)us[0]|((unsigned)us[1]<<16); pk.y=(unsigned)us[2]|((unsigned)us[3]<<16);
    pk.z=(unsigned)us[4]|((unsigned)us[5]<<16); pk.w=(unsigned)us[6]|((unsigned)us[7]<<16);
    *(uint4*)(&hs[(kc*64+pt)*8]) = pk;
  }
  __syncthreads();
  int lane=tid&63, wv=tid>>6, quad=lane>>4, l16=lane&15;
  int m0=wv*64;
  f32x4 acc[4][4];
  for (int a=0;a<4;a++)
    for (int b=0;b<4;b++)
      acc[a][b]=(f32x4){0.f,0.f,0.f,0.f};
  #pragma unroll
  for (int ks=0; ks<4; ++ks){
    bf16x8 bfr[4];
    #pragma unroll
    for (int nt=0; nt<4; ++nt) bfr[nt]=*(bf16x8*)(&hs[((ks*4+quad)*64 + nt*16 + l16)*8]);
    #pragma unroll
    for (int mt=0; mt<4; ++mt){
      bf16x8 afr = *(const bf16x8*)(&A.w2b[(m0+mt*16+l16)*128 + ks*32 + quad*8]);
      #pragma unroll
      for (int nt=0; nt<4; ++nt)
        acc[mt][nt]=__builtin_amdgcn_mfma_f32_16x16x32_bf16(afr, bfr[nt], acc[mt][nt], 0,0,0);
    }
  }
  bool uni = (segp[0]==segp[63]); int seg0=segp[0];
  size_t tb = (size_t)blockIdx.x*16384;
  #pragma unroll
  for (int mt=0;mt<4;++mt){
    int cout0=m0+mt*16+quad*4;
    int kg=cout0>>3, sub=cout0&7;
    float fv[4][4];
    #pragma unroll
    for (int nt=0;nt<4;++nt)
      #pragma unroll
      for (int r=0;r<4;++r)
        fv[nt][r]=fmaf(a2s[cout0+r], acc[mt][nt][r], c2s[cout0+r]);
    #pragma unroll
    for (int nt=0;nt<4;++nt){
      int ptl=nt*16+l16;
      uint2 pk;
      pk.x=(unsigned)f2bf(fv[nt][0])|((unsigned)f2bf(fv[nt][1])<<16);
      pk.y=(unsigned)f2bf(fv[nt][2])|((unsigned)f2bf(fv[nt][3])<<16);
      *(uint2*)&A.fbufp[tb + (size_t)((kg*64+ptl)*8+sub)] = pk;
    }
    #pragma unroll
    for (int r=0;r<4;++r){
      if (uni){
        float mv=fmaxf(fmaxf(fv[0][r],fv[1][r]),fmaxf(fv[2][r],fv[3][r]));
        #pragma unroll
        for (int off=8;off>=1;off>>=1) mv=fmaxf(mv, __shfl_xor(mv,off));
        if (l16==0) atomicMax(&A.gkeys[seg0*256+cout0+r], f2key(mv));
      } else {
        #pragma unroll
        for (int nt=0;nt<4;++nt)
          atomicMax(&A.gkeys[segp[nt*16+l16]*256+cout0+r], f2key(fv[nt][r]));
      }
    }
  }
}

// ---------------- cseg[seg][cout] = W3[:, :256] @ gs(seg) ----------------
__global__ void k_cseg(Args A){
  int seg = blockIdx.x>>1; int cout = (blockIdx.x&1)*256 + threadIdx.x;
  __shared__ float gs[256];
  gs[threadIdx.x] = key2f(A.gkeys[seg*256+threadIdx.x]);
  __syncthreads();
  const float* wrow = A.W3 + (size_t)cout*512;
  float s=0.f;
  #pragma unroll 8
  for (int k=0;k<256;k++) s = fmaf(wrow[k], gs[k], s);
  A.cseg[seg*512+cout]=s;
}

// ---------------- L3: m97-style 128x128 tile, K=256, small LDS -> multi-block/CU ----------------
// grid(4 mgrp, 1024 pt), 256 thr = 4 waves; wave (mq=wv&1, nq=wv>>1) -> 64x64 quadrant.
__global__ __launch_bounds__(256) void k_l3(Args A){
  __shared__ unsigned short As[4*128*8];   // 8 KB [kg][crel][8]
  __shared__ unsigned short Bs[4*128*8];   // 8 KB [kg][ptl][8]
  __shared__ int offs_s[NSEG+1]; __shared__ short segp[128];
  int tid=threadIdx.x, mbase=blockIdx.x*128, bpt=blockIdx.y;
  int lane=tid&63, wv=tid>>6, quad=lane>>4, l16=lane&15;
  int mq=wv&1, nq=wv>>1;
  auto stage = [&](int ks){
    #pragma unroll
    for (int i=0;i<4;++i){
      int ch=wv*4+i;
      if (ch<8){
        int kg=ch>>1, s=ch&1;
        const char* src=(const char*)A.w3p + ((size_t)((ks*4+kg)*512 + mbase + s*64)*8)*2 + lane*16;
        gl16(src, (char*)As + kg*2048 + s*1024);
      } else {
        int c2=ch-8, kg=c2>>1, h=c2&1;
        const char* src=(const char*)(A.fbufp + (size_t)(2*bpt+h)*16384) + (size_t)(ks*4+kg)*1024 + lane*16;
        gl16(src, (char*)Bs + kg*2048 + h*1024);
      }
    }
  };
  stage(0);
  if (tid<=NSEG) offs_s[tid]=A.offs[tid];
  f32x4 acc[4][4];
  for (int a=0;a<4;a++)
    for (int b=0;b<4;b++)
      acc[a][b]=(f32x4){0.f,0.f,0.f,0.f};
  for (int ks=0;;){
    __syncthreads();
    if (ks==0 && tid<128){ int gp=bpt*128+tid, s=0; while (gp>=offs_s[s+1]) s++; segp[tid]=(short)s; }
    bf16x8 afr[4], bfr[4];
    #pragma unroll
    for (int mt=0;mt<4;++mt) afr[mt]=*(bf16x8*)(&As[(quad*128 + mq*64 + mt*16 + l16)*8]);
    #pragma unroll
    for (int nt=0;nt<4;++nt) bfr[nt]=*(bf16x8*)(&Bs[(quad*128 + nq*64 + nt*16 + l16)*8]);
    #pragma unroll
    for (int mt=0;mt<4;++mt)
      #pragma unroll
      for (int nt=0;nt<4;++nt)
        acc[mt][nt]=__builtin_amdgcn_mfma_f32_16x16x32_bf16(afr[mt], bfr[nt], acc[mt][nt], 0,0,0);
    if (++ks==8) break;
    __syncthreads();
    stage(ks);
  }
  bool uni=(segp[0]==segp[127]); int seg0=segp[0];
  #pragma unroll
  for (int mt=0;mt<4;++mt){
    int cout0=mbase + mq*64 + mt*16 + quad*4;
    int kg=cout0>>3, sub=cout0&7;
    float sa[4],sc[4],csr[4];
    #pragma unroll
    for (int r=0;r<4;++r){ sa[r]=A.a3[cout0+r]; sc[r]=A.c3[cout0+r]; }
    if (uni){
      #pragma unroll
      for (int r=0;r<4;++r) csr[r]=A.cseg[seg0*512+cout0+r];
    }
    #pragma unroll
    for (int nt=0;nt<4;++nt){
      int ptl=nq*64+nt*16+l16;
      unsigned short us[4];
      #pragma unroll
      for (int r=0;r<4;++r){
        float cv = uni? csr[r] : A.cseg[segp[ptl]*512+cout0+r];
        float hv = fmaxf(fmaf(sa[r], acc[mt][nt][r]+cv, sc[r]), 0.f);
        us[r]=f2bf(hv);
      }
      uint2 pk;
      pk.x=(unsigned)us[0]|((unsigned)us[1]<<16);
      pk.y=(unsigned)us[2]|((unsigned)us[3]<<16);
      size_t tile=(size_t)(2*bpt + (ptl>>6));
      *(uint2*)&A.h3p[tile*32768 + (size_t)((kg*64+(ptl&63))*8+sub)] = pk;
    }
  }
}

// ---------------- L4: m97-style 128x128 tile, K=512 -> BN + segmax ----------------
// grid(8 mgrp, 1024 pt), 256 thr.
__global__ __launch_bounds__(256) void k_l4(Args A){
  __shared__ unsigned short As[4*128*8];   // 8 KB
  __shared__ unsigned short Bs[4*128*8];   // 8 KB
  __shared__ int offs_s[NSEG+1]; __shared__ short segp[128];
  int tid=threadIdx.x, mbase=blockIdx.x*128, bpt=blockIdx.y;
  int lane=tid&63, wv=tid>>6, quad=lane>>4, l16=lane&15;
  int mq=wv&1, nq=wv>>1;
  auto stage = [&](int ks){
    #pragma unroll
    for (int i=0;i<4;++i){
      int ch=wv*4+i;
      if (ch<8){
        int kg=ch>>1, s=ch&1;
        const char* src=(const char*)A.w4p + ((size_t)((ks*4+kg)*1024 + mbase + s*64)*8)*2 + lane*16;
        gl16(src, (char*)As + kg*2048 + s*1024);
      } else {
        int c2=ch-8, kg=c2>>1, h=c2&1;
        const char* src=(const char*)(A.h3p + (size_t)(2*bpt+h)*32768) + (size_t)(ks*4+kg)*1024 + lane*16;
        gl16(src, (char*)Bs + kg*2048 + h*1024);
      }
    }
  };
  stage(0);
  if (tid<=NSEG) offs_s[tid]=A.offs[tid];
  f32x4 acc[4][4];
  for (int a=0;a<4;a++)
    for (int b=0;b<4;b++)
      acc[a][b]=(f32x4){0.f,0.f,0.f,0.f};
  for (int ks=0;;){
    __syncthreads();
    if (ks==0 && tid<128){ int gp=bpt*128+tid, s=0; while (gp>=offs_s[s+1]) s++; segp[tid]=(short)s; }
    bf16x8 afr[4], bfr[4];
    #pragma unroll
    for (int mt=0;mt<4;++mt) afr[mt]=*(bf16x8*)(&As[(quad*128 + mq*64 + mt*16 + l16)*8]);
    #pragma unroll
    for (int nt=0;nt<4;++nt) bfr[nt]=*(bf16x8*)(&Bs[(quad*128 + nq*64 + nt*16 + l16)*8]);
    #pragma unroll
    for (int mt=0;mt<4;++mt)
      #pragma unroll
      for (int nt=0;nt<4;++nt)
        acc[mt][nt]=__builtin_amdgcn_mfma_f32_16x16x32_bf16(afr[mt], bfr[nt], acc[mt][nt], 0,0,0);
    if (++ks==16) break;
    __syncthreads();
    stage(ks);
  }
  bool uni=(segp[0]==segp[127]); int seg0=segp[0];
  #pragma unroll
  for (int mt=0;mt<4;++mt){
    #pragma unroll
    for (int r=0;r<4;++r){
      int cout=mbase + mq*64 + mt*16 + quad*4 + r;
      float sa=A.a4[cout], sc=A.c4[cout];
      float mv=-3.4e38f;
      #pragma unroll
      for (int nt=0;nt<4;++nt){
        float fv=fmaf(sa, acc[mt][nt][r], sc);
        if (uni) mv=fmaxf(mv,fv);
        else atomicMax(&A.vkeys[segp[nq*64+nt*16+l16]*1024+cout], f2key(fv));
      }
      if (uni){
        #pragma unroll
        for (int off=8;off>=1;off>>=1) mv=fmaxf(mv, __shfl_xor(mv,off));
        if (l16==0) atomicMax(&A.vkeys[seg0*1024+cout], f2key(mv));
      }
    }
  }
}

// ---------------- decode ----------------
__global__ void k_final(Args A){
  int i=blockIdx.x*256+threadIdx.x;
  if (i<NSEG*1024) A.out[i]=key2f(A.vkeys[i]);
}

extern "C" void kernel_launch(void* const* d_in, const int* in_sizes, int n_in,
                              void* d_out, int out_size, void* d_ws, size_t ws_size,
                              hipStream_t stream){
  Args A;
  A.x  =(const float*)d_in[0];  A.npts=(const int*)d_in[1];
  A.W1 =(const float*)d_in[2];  A.b1 =(const float*)d_in[3];
  A.g1 =(const float*)d_in[4];  A.be1=(const float*)d_in[5];
  A.m1 =(const float*)d_in[6];  A.v1 =(const float*)d_in[7];
  A.W2 =(const float*)d_in[8];  A.b2 =(const float*)d_in[9];
  A.g2 =(const float*)d_in[10]; A.be2=(const float*)d_in[11];
  A.m2 =(const float*)d_in[12]; A.v2 =(const float*)d_in[13];
  A.W3 =(const float*)d_in[14]; A.b3 =(const float*)d_in[15];
  A.g3 =(const float*)d_in[16]; A.be3=(const float*)d_in[17];
  A.m3 =(const float*)d_in[18]; A.v3 =(const float*)d_in[19];
  A.W4 =(const float*)d_in[20]; A.b4 =(const float*)d_in[21];
  A.g4 =(const float*)d_in[22]; A.be4=(const float*)d_in[23];
  A.m4 =(const float*)d_in[24]; A.v4 =(const float*)d_in[25];

  char* w=(char*)d_ws;
  auto alloc=[&](size_t b)->void*{ void* p=(void*)w; w += (b+255)&~(size_t)255; return p; };
  A.offs =(int*)alloc((NSEG+1)*4);
  A.a1=(float*)alloc(128*4);  A.c1=(float*)alloc(128*4);
  A.a2=(float*)alloc(256*4);  A.c2=(float*)alloc(256*4);
  A.a3=(float*)alloc(512*4);  A.c3=(float*)alloc(512*4);
  A.a4=(float*)alloc(1024*4); A.c4=(float*)alloc(1024*4);
  A.gkeys=(unsigned int*)alloc(NSEG*256*4);
  A.vkeys=(unsigned int*)alloc(NSEG*1024*4);
  A.cseg =(float*)alloc(NSEG*512*4);
  A.w2b=(unsigned short*)alloc(256*128*2);
  A.w3p=(unsigned short*)alloc(131072*2);
  A.w4p=(unsigned short*)alloc(524288*2);
  A.fbufp=(unsigned short*)alloc((size_t)2048*16384*2);  // 64 MB
  A.h3p  =(unsigned short*)alloc((size_t)2048*32768*2);  // 128 MB
  A.out=(float*)d_out;

  k_setup<<<dim3(1),dim3(256),0,stream>>>(A);
  k_conv <<<dim3(2688),dim3(256),0,stream>>>(A);
  k_l12  <<<dim3(NTOT/64),dim3(256),0,stream>>>(A);
  k_cseg <<<dim3(32),dim3(256),0,stream>>>(A);
  k_l3   <<<dim3(4,NTOT/128),dim3(256),0,stream>>>(A);
  k_l4   <<<dim3(8,NTOT/128),dim3(256),0,stream>>>(A);
  k_final<<<dim3(64),dim3(256),0,stream>>>(A);
}

// Round 8
// 736.690 us; speedup vs baseline: 1.3511x; 1.3511x over previous
//
#include <hip/hip_runtime.h>
#include <hip/hip_bf16.h>
#include <stdint.h>

#define NTOT 131072
#define NSEG 16
#define EPSV 1e-5f

typedef __attribute__((ext_vector_type(8))) short bf16x8;
typedef __attribute__((ext_vector_type(4))) float f32x4;

struct Args {
  const float* x; const int* npts;
  const float *W1,*b1,*g1,*be1,*m1,*v1;
  const float *W2,*b2,*g2,*be2,*m2,*v2;
  const float *W3,*b3,*g3,*be3,*m3,*v3;
  const float *W4,*b4,*g4,*be4,*m4,*v4;
  int* offs;
  float *a1,*c1,*a2,*c2,*a3,*c3,*a4,*c4;
  unsigned int *gkeys,*vkeys;
  unsigned short *w2b,*w3b,*w4b;
  unsigned short *fbufp;   // [2048 tiles][32 kg][64 pt][8]
  unsigned short *h3p;     // [2048 tiles][64 kg][64 pt][8]
  float* cseg;             // [16][512] = W3[:, :256] @ gs(seg)
  float* out;
};

__device__ inline unsigned int f2key(float f){ unsigned u=__float_as_uint(f); return (u&0x80000000u)? ~u : (u|0x80000000u); }
__device__ inline float key2f(unsigned k){ unsigned u=(k&0x80000000u)? (k^0x80000000u) : ~k; return __uint_as_float(u); }
__device__ inline unsigned short f2bf(float f){ __hip_bfloat16 h=__float2bfloat16(f); return *(unsigned short*)&h; }

__device__ inline void gl16(const void* g, void* l){
  __builtin_amdgcn_global_load_lds((const __attribute__((address_space(1))) unsigned int*)g,
                                   (__attribute__((address_space(3))) unsigned int*)l, 16, 0, 0);
}

// ---------------- setup ----------------
__global__ void k_setup(Args A){
  int tid = threadIdx.x;
  if (tid==0){ int s=0; A.offs[0]=0; for (int i=0;i<NSEG;i++){ s+=A.npts[i]; A.offs[i+1]=s; } }
  for (int c=tid;c<128;c+=256){ float a=A.g1[c]*rsqrtf(A.v1[c]+EPSV); A.a1[c]=a; A.c1[c]=A.be1[c]+a*(A.b1[c]-A.m1[c]); }
  for (int c=tid;c<256;c+=256){ float a=A.g2[c]*rsqrtf(A.v2[c]+EPSV); A.a2[c]=a; A.c2[c]=A.be2[c]+a*(A.b2[c]-A.m2[c]); }
  for (int c=tid;c<512;c+=256){ float a=A.g3[c]*rsqrtf(A.v3[c]+EPSV); A.a3[c]=a; A.c3[c]=A.be3[c]+a*(A.b3[c]-A.m3[c]); }
  for (int c=tid;c<1024;c+=256){ float a=A.g4[c]*rsqrtf(A.v4[c]+EPSV); A.a4[c]=a; A.c4[c]=A.be4[c]+a*(A.b4[c]-A.m4[c]); }
  for (int i=tid;i<NSEG*256;i+=256)  A.gkeys[i]=0u;
  for (int i=tid;i<NSEG*1024;i+=256) A.vkeys[i]=0u;
}

// ---------------- weights fp32 -> bf16 ----------------
__global__ void k_conv(Args A){
  const int n1=256*128, n2=512*512, n3=1024*512;
  for (int i = blockIdx.x*256+threadIdx.x; i < n1+n2+n3; i += gridDim.x*256){
    if (i<n1)          A.w2b[i]      = f2bf(A.W2[i]);
    else if (i<n1+n2)  A.w3b[i-n1]   = f2bf(A.W3[i-n1]);
    else               A.w4b[i-n1-n2]= f2bf(A.W4[i-n1-n2]);
  }
}

// ---------------- L1 (VALU) + L2 (MFMA) + BN -> fbufp packed + gkeys ----------------
__global__ __launch_bounds__(256) void k_l12(Args A){
  __shared__ float w1s[384], a1s[128], c1s[128], a2s[256], c2s[256];
  __shared__ float xs[3][64];
  __shared__ int offs_s[NSEG+1], segp[64];
  __shared__ unsigned short hs[16*64*8];
  int tid=threadIdx.x, pt0=blockIdx.x*64;
  for (int i=tid;i<384;i+=256) w1s[i]=A.W1[i];
  if (tid<128){ a1s[tid]=A.a1[tid]; c1s[tid]=A.c1[tid]; }
  a2s[tid]=A.a2[tid]; c2s[tid]=A.c2[tid];
  if (tid<=NSEG) offs_s[tid]=A.offs[tid];
  if (tid<64){ xs[0][tid]=A.x[pt0+tid]; xs[1][tid]=A.x[NTOT+pt0+tid]; xs[2][tid]=A.x[2*NTOT+pt0+tid]; }
  __syncthreads();
  if (tid<64){ int gp=pt0+tid, s=0; while (gp>=offs_s[s+1]) s++; segp[tid]=s; }
  for (int pair=tid; pair<1024; pair+=256){
    int pt=pair&63, kc=pair>>6;
    float x0=xs[0][pt], x1=xs[1][pt], x2=xs[2][pt];
    unsigned short us[8];
    #pragma unroll
    for (int j=0;j<8;j++){
      int cin=kc*8+j;
      float v = fmaf(w1s[cin*3],x0, fmaf(w1s[cin*3+1],x1, w1s[cin*3+2]*x2));
      v = fmaxf(fmaf(a1s[cin],v,c1s[cin]), 0.f);
      us[j]=f2bf(v);
    }
    uint4 pk;
    pk.x=(unsigned)us[0]|((unsigned)us[1]<<16); pk.y=(unsigned)us[2]|((unsigned)us[3]<<16);
    pk.z=(unsigned)us[4]|((unsigned)us[5]<<16); pk.w=(unsigned)us[6]|((unsigned)us[7]<<16);
    *(uint4*)(&hs[(kc*64+pt)*8]) = pk;
  }
  __syncthreads();
  int lane=tid&63, wv=tid>>6, quad=lane>>4, l16=lane&15;
  int m0=wv*64;
  f32x4 acc[4][4];
  for (int a=0;a<4;a++)
    for (int b=0;b<4;b++)
      acc[a][b]=(f32x4){0.f,0.f,0.f,0.f};
  #pragma unroll
  for (int ks=0; ks<4; ++ks){
    bf16x8 bfr[4];
    #pragma unroll
    for (int nt=0; nt<4; ++nt) bfr[nt]=*(bf16x8*)(&hs[((ks*4+quad)*64 + nt*16 + l16)*8]);
    #pragma unroll
    for (int mt=0; mt<4; ++mt){
      bf16x8 afr = *(const bf16x8*)(&A.w2b[(m0+mt*16+l16)*128 + ks*32 + quad*8]);
      #pragma unroll
      for (int nt=0; nt<4; ++nt)
        acc[mt][nt]=__builtin_amdgcn_mfma_f32_16x16x32_bf16(afr, bfr[nt], acc[mt][nt], 0,0,0);
    }
  }
  bool uni = (segp[0]==segp[63]); int seg0=segp[0];
  size_t tb = (size_t)blockIdx.x*16384;
  #pragma unroll
  for (int mt=0;mt<4;++mt){
    int cout0=m0+mt*16+quad*4;
    int kg=cout0>>3, sub=cout0&7;
    float fv[4][4];
    #pragma unroll
    for (int nt=0;nt<4;++nt)
      #pragma unroll
      for (int r=0;r<4;++r)
        fv[nt][r]=fmaf(a2s[cout0+r], acc[mt][nt][r], c2s[cout0+r]);
    #pragma unroll
    for (int nt=0;nt<4;++nt){
      int ptl=nt*16+l16;
      uint2 pk;
      pk.x=(unsigned)f2bf(fv[nt][0])|((unsigned)f2bf(fv[nt][1])<<16);
      pk.y=(unsigned)f2bf(fv[nt][2])|((unsigned)f2bf(fv[nt][3])<<16);
      *(uint2*)&A.fbufp[tb + (size_t)((kg*64+ptl)*8+sub)] = pk;
    }
    #pragma unroll
    for (int r=0;r<4;++r){
      if (uni){
        float mv=fmaxf(fmaxf(fv[0][r],fv[1][r]),fmaxf(fv[2][r],fv[3][r]));
        #pragma unroll
        for (int off=8;off>=1;off>>=1) mv=fmaxf(mv, __shfl_xor(mv,off));
        if (l16==0) atomicMax(&A.gkeys[seg0*256+cout0+r], f2key(mv));
      } else {
        #pragma unroll
        for (int nt=0;nt<4;++nt)
          atomicMax(&A.gkeys[segp[nt*16+l16]*256+cout0+r], f2key(fv[nt][r]));
      }
    }
  }
}

// ---------------- cseg[seg][cout] = W3[:, :256] @ gs(seg) ----------------
__global__ void k_cseg(Args A){
  int seg = blockIdx.x>>1; int cout = (blockIdx.x&1)*256 + threadIdx.x;
  __shared__ float gs[256];
  gs[threadIdx.x] = key2f(A.gkeys[seg*256+threadIdx.x]);
  __syncthreads();
  const float* wrow = A.W3 + (size_t)cout*512;
  float s=0.f;
  #pragma unroll 8
  for (int k=0;k<256;k++) s = fmaf(wrow[k], gs[k], s);
  A.cseg[seg*512+cout]=s;
}

// ---------------- L3: weights-in-registers, stream 8 pt-tiles, dbuf gl16 ----------------
__global__ __launch_bounds__(512,2) void k_l3(Args A){
  __shared__ unsigned short xb[2*16384];     // 2 x 32 KB f-tile dbuf
  __shared__ int offs_s[NSEG+1]; __shared__ short segp8[8][64];
  int tid=threadIdx.x, ptr0=blockIdx.x*8;
  int lane=tid&63, wv=tid>>6, quad=lane>>4, l16=lane&15;
  {
    const char* src=(const char*)A.fbufp + (size_t)ptr0*32768;
    #pragma unroll
    for (int c=0;c<4;++c) gl16(src + (wv*4+c)*1024 + lane*16, (char*)xb + (wv*4+c)*1024);
  }
  if (tid<=NSEG) offs_s[tid]=A.offs[tid];
  __syncthreads();
  { int t=tid>>6, pt=tid&63; int gp=ptr0*64 + t*64 + pt; int s=0; while (gp>=offs_s[s+1]) s++; segp8[t][pt]=(short)s; }
  bf16x8 afr[4][8];
  #pragma unroll
  for (int mt=0;mt<4;++mt)
    #pragma unroll
    for (int ksl=0;ksl<8;++ksl)
      afr[mt][ksl]=*(const bf16x8*)(&A.w3b[(size_t)(wv*64+mt*16+l16)*512 + 256 + ksl*32 + quad*8]);
  float sa[4][4], sc[4][4];
  #pragma unroll
  for (int mt=0;mt<4;++mt)
    #pragma unroll
    for (int r=0;r<4;++r){ int c=wv*64+mt*16+quad*4+r; sa[mt][r]=A.a3[c]; sc[mt][r]=A.c3[c]; }

  for (int t=0;t<8;++t){
    __syncthreads();
    if (t<7){
      const char* src=(const char*)A.fbufp + (size_t)(ptr0+t+1)*32768;
      char* dst=(char*)xb + ((t+1)&1)*32768;
      #pragma unroll
      for (int c=0;c<4;++c) gl16(src + (wv*4+c)*1024 + lane*16, dst + (wv*4+c)*1024);
    }
    const unsigned short* xt = xb + (t&1)*16384;
    f32x4 acc[4][4];
    for (int a=0;a<4;a++)
      for (int b=0;b<4;b++)
        acc[a][b]=(f32x4){0.f,0.f,0.f,0.f};
    #pragma unroll
    for (int ksl=0; ksl<8; ++ksl){
      bf16x8 bfr[4];
      #pragma unroll
      for (int nt=0; nt<4; ++nt) bfr[nt]=*(bf16x8*)(&xt[((ksl*4+quad)*64 + nt*16 + l16)*8]);
      #pragma unroll
      for (int mt=0; mt<4; ++mt)
        #pragma unroll
        for (int nt=0; nt<4; ++nt)
          acc[mt][nt]=__builtin_amdgcn_mfma_f32_16x16x32_bf16(afr[mt][ksl], bfr[nt], acc[mt][nt], 0,0,0);
    }
    int tg=ptr0+t;
    bool uni=(segp8[t][0]==segp8[t][63]); int seg0=segp8[t][0];
    size_t tb=(size_t)tg*32768;
    #pragma unroll
    for (int mt=0;mt<4;++mt){
      int cout0=wv*64+mt*16+quad*4;
      int kg=cout0>>3, sub=cout0&7;
      float csr[4];
      if (uni){
        #pragma unroll
        for (int r=0;r<4;++r) csr[r]=A.cseg[seg0*512+cout0+r];
      }
      #pragma unroll
      for (int nt=0;nt<4;++nt){
        int ptl=nt*16+l16;
        unsigned short us[4];
        #pragma unroll
        for (int r=0;r<4;++r){
          float cv = uni? csr[r] : A.cseg[segp8[t][ptl]*512+cout0+r];
          float hv = fmaxf(fmaf(sa[mt][r], acc[mt][nt][r]+cv, sc[mt][r]), 0.f);
          us[r]=f2bf(hv);
        }
        uint2 pk;
        pk.x=(unsigned)us[0]|((unsigned)us[1]<<16);
        pk.y=(unsigned)us[2]|((unsigned)us[3]<<16);
        *(uint2*)&A.h3p[tb + (size_t)((kg*64+ptl)*8+sub)] = pk;
      }
    }
  }
}

// ---------------- L4: weights PINNED in registers, stream 8 pt-tiles, dbuf gl16 ----------------
// grid (4 cgrp, 256 ptrange) x 512 thr. Wave wv -> couts cgrp*256+[wv*32,+32), K=512.
// asm pin forces the 128 weight VGPRs resident (r6: compiler rematerialized at VGPR=112,
// re-pulling 32KB/wave/tile through L1 inside the MFMA loop -> 16% MfmaUtil ceiling).
__global__ __launch_bounds__(512,2) void k_l4(Args A){
  __shared__ unsigned short xb[2*32768];     // 2 x 64 KB h3-tile dbuf
  __shared__ int offs_s[NSEG+1]; __shared__ short segp8[8][64];
  int tid=threadIdx.x, cgrp=blockIdx.x, ptr0=blockIdx.y*8;
  int lane=tid&63, wv=tid>>6, quad=lane>>4, l16=lane&15;
  {
    const char* src=(const char*)A.h3p + (size_t)ptr0*65536;
    #pragma unroll
    for (int c=0;c<8;++c) gl16(src + (wv*8+c)*1024 + lane*16, (char*)xb + (wv*8+c)*1024);
  }
  if (tid<=NSEG) offs_s[tid]=A.offs[tid];
  __syncthreads();
  { int t=tid>>6, pt=tid&63; int gp=ptr0*64 + t*64 + pt; int s=0; while (gp>=offs_s[s+1]) s++; segp8[t][pt]=(short)s; }
  bf16x8 afr[2][16];
  #pragma unroll
  for (int mt=0;mt<2;++mt)
    #pragma unroll
    for (int ksl=0;ksl<16;++ksl)
      afr[mt][ksl]=*(const bf16x8*)(&A.w4b[(size_t)(cgrp*256+wv*32+mt*16+l16)*512 + ksl*32 + quad*8]);
  // pin: opaque to the optimizer -> cannot be rematerialized/spilled-by-choice
  #pragma unroll
  for (int mt=0;mt<2;++mt)
    #pragma unroll
    for (int ksl=0;ksl<16;++ksl)
      asm volatile("" : "+v"(afr[mt][ksl]));
  float sa[2][4], sc[2][4];
  #pragma unroll
  for (int mt=0;mt<2;++mt)
    #pragma unroll
    for (int r=0;r<4;++r){ int c=cgrp*256+wv*32+mt*16+quad*4+r; sa[mt][r]=A.a4[c]; sc[mt][r]=A.c4[c]; }

  for (int t=0;t<8;++t){
    __syncthreads();
    if (t<7){
      const char* src=(const char*)A.h3p + (size_t)(ptr0+t+1)*65536;
      char* dst=(char*)xb + ((t+1)&1)*65536;
      #pragma unroll
      for (int c=0;c<8;++c) gl16(src + (wv*8+c)*1024 + lane*16, dst + (wv*8+c)*1024);
    }
    const unsigned short* xt = xb + (t&1)*32768;
    f32x4 acc[2][4];
    for (int a=0;a<2;a++)
      for (int b=0;b<4;b++)
        acc[a][b]=(f32x4){0.f,0.f,0.f,0.f};
    #pragma unroll
    for (int ksl=0; ksl<16; ++ksl){
      bf16x8 bfr[4];
      #pragma unroll
      for (int nt=0; nt<4; ++nt) bfr[nt]=*(bf16x8*)(&xt[((ksl*4+quad)*64 + nt*16 + l16)*8]);
      #pragma unroll
      for (int mt=0; mt<2; ++mt)
        #pragma unroll
        for (int nt=0; nt<4; ++nt)
          acc[mt][nt]=__builtin_amdgcn_mfma_f32_16x16x32_bf16(afr[mt][ksl], bfr[nt], acc[mt][nt], 0,0,0);
    }
    bool uni=(segp8[t][0]==segp8[t][63]); int seg0=segp8[t][0];
    #pragma unroll
    for (int mt=0;mt<2;++mt){
      #pragma unroll
      for (int r=0;r<4;++r){
        int cout=cgrp*256+wv*32+mt*16+quad*4+r;
        float mv=-3.4e38f;
        #pragma unroll
        for (int nt=0;nt<4;++nt){
          float fv=fmaf(sa[mt][r], acc[mt][nt][r], sc[mt][r]);
          if (uni) mv=fmaxf(mv,fv);
          else atomicMax(&A.vkeys[segp8[t][nt*16+l16]*1024+cout], f2key(fv));
        }
        if (uni){
          #pragma unroll
          for (int off=8;off>=1;off>>=1) mv=fmaxf(mv, __shfl_xor(mv,off));
          if (l16==0) atomicMax(&A.vkeys[seg0*1024+cout], f2key(mv));
        }
      }
    }
  }
}

// ---------------- decode ----------------
__global__ void k_final(Args A){
  int i=blockIdx.x*256+threadIdx.x;
  if (i<NSEG*1024) A.out[i]=key2f(A.vkeys[i]);
}

extern "C" void kernel_launch(void* const* d_in, const int* in_sizes, int n_in,
                              void* d_out, int out_size, void* d_ws, size_t ws_size,
                              hipStream_t stream){
  Args A;
  A.x  =(const float*)d_in[0];  A.npts=(const int*)d_in[1];
  A.W1 =(const float*)d_in[2];  A.b1 =(const float*)d_in[3];
  A.g1 =(const float*)d_in[4];  A.be1=(const float*)d_in[5];
  A.m1 =(const float*)d_in[6];  A.v1 =(const float*)d_in[7];
  A.W2 =(const float*)d_in[8];  A.b2 =(const float*)d_in[9];
  A.g2 =(const float*)d_in[10]; A.be2=(const float*)d_in[11];
  A.m2 =(const float*)d_in[12]; A.v2 =(const float*)d_in[13];
  A.W3 =(const float*)d_in[14]; A.b3 =(const float*)d_in[15];
  A.g3 =(const float*)d_in[16]; A.be3=(const float*)d_in[17];
  A.m3 =(const float*)d_in[18]; A.v3 =(const float*)d_in[19];
  A.W4 =(const float*)d_in[20]; A.b4 =(const float*)d_in[21];
  A.g4 =(const float*)d_in[22]; A.be4=(const float*)d_in[23];
  A.m4 =(const float*)d_in[24]; A.v4 =(const float*)d_in[25];

  char* w=(char*)d_ws;
  auto alloc=[&](size_t b)->void*{ void* p=(void*)w; w += (b+255)&~(size_t)255; return p; };
  A.offs =(int*)alloc((NSEG+1)*4);
  A.a1=(float*)alloc(128*4);  A.c1=(float*)alloc(128*4);
  A.a2=(float*)alloc(256*4);  A.c2=(float*)alloc(256*4);
  A.a3=(float*)alloc(512*4);  A.c3=(float*)alloc(512*4);
  A.a4=(float*)alloc(1024*4); A.c4=(float*)alloc(1024*4);
  A.gkeys=(unsigned int*)alloc(NSEG*256*4);
  A.vkeys=(unsigned int*)alloc(NSEG*1024*4);
  A.cseg =(float*)alloc(NSEG*512*4);
  A.w2b=(unsigned short*)alloc(256*128*2);
  A.w3b=(unsigned short*)alloc(512*512*2);
  A.w4b=(unsigned short*)alloc(1024*512*2);
  A.fbufp=(unsigned short*)alloc((size_t)2048*16384*2);  // 64 MB
  A.h3p  =(unsigned short*)alloc((size_t)2048*32768*2);  // 128 MB
  A.out=(float*)d_out;

  k_setup<<<dim3(1),dim3(256),0,stream>>>(A);
  k_conv <<<dim3(3200),dim3(256),0,stream>>>(A);
  k_l12  <<<dim3(NTOT/64),dim3(256),0,stream>>>(A);
  k_cseg <<<dim3(32),dim3(256),0,stream>>>(A);
  k_l3   <<<dim3(256),dim3(512),0,stream>>>(A);
  k_l4   <<<dim3(4,256),dim3(512),0,stream>>>(A);
  k_final<<<dim3(64),dim3(256),0,stream>>>(A);
}

// Round 10
// 683.794 us; speedup vs baseline: 1.4556x; 1.0774x over previous
//
#include <hip/hip_runtime.h>
#include <hip/hip_bf16.h>
#include <stdint.h>

#define NTOT 131072
#define NSEG 16
#define EPSV 1e-5f

typedef __attribute__((ext_vector_type(8))) short bf16x8;
typedef __attribute__((ext_vector_type(4))) float f32x4;

struct Args {
  const float* x; const int* npts;
  const float *W1,*b1,*g1,*be1,*m1,*v1;
  const float *W2,*b2,*g2,*be2,*m2,*v2;
  const float *W3,*b3,*g3,*be3,*m3,*v3;
  const float *W4,*b4,*g4,*be4,*m4,*v4;
  int* offs;
  float *a1,*c1,*a2,*c2,*a3,*c3,*a4,*c4;
  unsigned int *gkeys,*vkeys;
  unsigned short *w2b;
  unsigned short *w3p;     // [8 ks][4 kg][512 cout][8]  (f-part of W3, k=256..512)
  unsigned short *w4p;     // [16 ks][4 kg][1024 cout][8]
  unsigned short *fbufp;   // [2048 tiles][32 kg][64 pt][8]
  unsigned short *h3p;     // [2048 tiles][64 kg][64 pt][8]
  float* cseg;             // [16][512] = W3[:, :256] @ gs(seg)
  float* out;
};

__device__ inline unsigned int f2key(float f){ unsigned u=__float_as_uint(f); return (u&0x80000000u)? ~u : (u|0x80000000u); }
__device__ inline float key2f(unsigned k){ unsigned u=(k&0x80000000u)? (k^0x80000000u) : ~k; return __uint_as_float(u); }
__device__ inline unsigned short f2bf(float f){ __hip_bfloat16 h=__float2bfloat16(f); return *(unsigned short*)&h; }

__device__ inline void gl16(const void* g, void* l){
  __builtin_amdgcn_global_load_lds((const __attribute__((address_space(1))) unsigned int*)g,
                                   (__attribute__((address_space(3))) unsigned int*)l, 16, 0, 0);
}

// ---------------- setup ----------------
__global__ void k_setup(Args A){
  int tid = threadIdx.x;
  if (tid==0){ int s=0; A.offs[0]=0; for (int i=0;i<NSEG;i++){ s+=A.npts[i]; A.offs[i+1]=s; } }
  for (int c=tid;c<128;c+=256){ float a=A.g1[c]*rsqrtf(A.v1[c]+EPSV); A.a1[c]=a; A.c1[c]=A.be1[c]+a*(A.b1[c]-A.m1[c]); }
  for (int c=tid;c<256;c+=256){ float a=A.g2[c]*rsqrtf(A.v2[c]+EPSV); A.a2[c]=a; A.c2[c]=A.be2[c]+a*(A.b2[c]-A.m2[c]); }
  for (int c=tid;c<512;c+=256){ float a=A.g3[c]*rsqrtf(A.v3[c]+EPSV); A.a3[c]=a; A.c3[c]=A.be3[c]+a*(A.b3[c]-A.m3[c]); }
  for (int c=tid;c<1024;c+=256){ float a=A.g4[c]*rsqrtf(A.v4[c]+EPSV); A.a4[c]=a; A.c4[c]=A.be4[c]+a*(A.b4[c]-A.m4[c]); }
  for (int i=tid;i<NSEG*256;i+=256)  A.gkeys[i]=0u;
  for (int i=tid;i<NSEG*1024;i+=256) A.vkeys[i]=0u;
}

// ---------------- weights fp32 -> bf16 (w2b plain, w3p/w4p gl16-packed) ----------------
__global__ void k_conv(Args A){
  const int n1=256*128;        // 32768
  const int n2=8*4*512*8;      // 131072
  const int n3=16*4*1024*8;    // 524288
  for (int i = blockIdx.x*256+threadIdx.x; i < n1+n2+n3; i += gridDim.x*256){
    if (i<n1) A.w2b[i]=f2bf(A.W2[i]);
    else if (i<n1+n2){
      int o=i-n1; int j=o&7, cout=(o>>3)&511, g=o>>12; int ks=g>>2, kg=g&3;
      A.w3p[o]=f2bf(A.W3[(size_t)cout*512 + 256 + ks*32+kg*8+j]);
    } else {
      int o=i-n1-n2; int j=o&7, cout=(o>>3)&1023, g=o>>13; int ks=g>>2, kg=g&3;
      A.w4p[o]=f2bf(A.W4[(size_t)cout*512 + ks*32+kg*8+j]);
    }
  }
}

// ---------------- L1 (VALU) + L2 (MFMA) + BN -> fbufp packed + gkeys ----------------
__global__ __launch_bounds__(256) void k_l12(Args A){
  __shared__ float w1s[384], a1s[128], c1s[128], a2s[256], c2s[256];
  __shared__ float xs[3][64];
  __shared__ int offs_s[NSEG+1], segp[64];
  __shared__ unsigned short hs[16*64*8];
  int tid=threadIdx.x, pt0=blockIdx.x*64;
  for (int i=tid;i<384;i+=256) w1s[i]=A.W1[i];
  if (tid<128){ a1s[tid]=A.a1[tid]; c1s[tid]=A.c1[tid]; }
  a2s[tid]=A.a2[tid]; c2s[tid]=A.c2[tid];
  if (tid<=NSEG) offs_s[tid]=A.offs[tid];
  if (tid<64){ xs[0][tid]=A.x[pt0+tid]; xs[1][tid]=A.x[NTOT+pt0+tid]; xs[2][tid]=A.x[2*NTOT+pt0+tid]; }
  __syncthreads();
  if (tid<64){ int gp=pt0+tid, s=0; while (gp>=offs_s[s+1]) s++; segp[tid]=s; }
  for (int pair=tid; pair<1024; pair+=256){
    int pt=pair&63, kc=pair>>6;
    float x0=xs[0][pt], x1=xs[1][pt], x2=xs[2][pt];
    unsigned short us[8];
    #pragma unroll
    for (int j=0;j<8;j++){
      int cin=kc*8+j;
      float v = fmaf(w1s[cin*3],x0, fmaf(w1s[cin*3+1],x1, w1s[cin*3+2]*x2));
      v = fmaxf(fmaf(a1s[cin],v,c1s[cin]), 0.f);
      us[j]=f2bf(v);
    }
    uint4 pk;
    pk.x=(unsigned)us[0]|((unsigned)us[1]<<16); pk.y=(unsigned)us[2]|((unsigned)us[3]<<16);
    pk.z=(unsigned)us[4]|((unsigned)us[5]<<16); pk.w=(unsigned)us[6]|((unsigned)us[7]<<16);
    *(uint4*)(&hs[(kc*64+pt)*8]) = pk;
  }
  __syncthreads();
  int lane=tid&63, wv=tid>>6, quad=lane>>4, l16=lane&15;
  int m0=wv*64;
  f32x4 acc[4][4];
  for (int a=0;a<4;a++)
    for (int b=0;b<4;b++)
      acc[a][b]=(f32x4){0.f,0.f,0.f,0.f};
  #pragma unroll
  for (int ks=0; ks<4; ++ks){
    bf16x8 bfr[4];
    #pragma unroll
    for (int nt=0; nt<4; ++nt) bfr[nt]=*(bf16x8*)(&hs[((ks*4+quad)*64 + nt*16 + l16)*8]);
    #pragma unroll
    for (int mt=0; mt<4; ++mt){
      bf16x8 afr = *(const bf16x8*)(&A.w2b[(m0+mt*16+l16)*128 + ks*32 + quad*8]);
      #pragma unroll
      for (int nt=0; nt<4; ++nt)
        acc[mt][nt]=__builtin_amdgcn_mfma_f32_16x16x32_bf16(afr, bfr[nt], acc[mt][nt], 0,0,0);
    }
  }
  bool uni = (segp[0]==segp[63]); int seg0=segp[0];
  size_t tb = (size_t)blockIdx.x*16384;
  #pragma unroll
  for (int mt=0;mt<4;++mt){
    int cout0=m0+mt*16+quad*4;
    int kg=cout0>>3, sub=cout0&7;
    float fv[4][4];
    #pragma unroll
    for (int nt=0;nt<4;++nt)
      #pragma unroll
      for (int r=0;r<4;++r)
        fv[nt][r]=fmaf(a2s[cout0+r], acc[mt][nt][r], c2s[cout0+r]);
    #pragma unroll
    for (int nt=0;nt<4;++nt){
      int ptl=nt*16+l16;
      uint2 pk;
      pk.x=(unsigned)f2bf(fv[nt][0])|((unsigned)f2bf(fv[nt][1])<<16);
      pk.y=(unsigned)f2bf(fv[nt][2])|((unsigned)f2bf(fv[nt][3])<<16);
      *(uint2*)&A.fbufp[tb + (size_t)((kg*64+ptl)*8+sub)] = pk;
    }
    #pragma unroll
    for (int r=0;r<4;++r){
      if (uni){
        float mv=fmaxf(fmaxf(fv[0][r],fv[1][r]),fmaxf(fv[2][r],fv[3][r]));
        #pragma unroll
        for (int off=8;off>=1;off>>=1) mv=fmaxf(mv, __shfl_xor(mv,off));
        if (l16==0) atomicMax(&A.gkeys[seg0*256+cout0+r], f2key(mv));
      } else {
        #pragma unroll
        for (int nt=0;nt<4;++nt)
          atomicMax(&A.gkeys[segp[nt*16+l16]*256+cout0+r], f2key(fv[nt][r]));
      }
    }
  }
}

// ---------------- cseg[seg][cout] = W3[:, :256] @ gs(seg) ----------------
__global__ void k_cseg(Args A){
  int seg = blockIdx.x>>1; int cout = (blockIdx.x&1)*256 + threadIdx.x;
  __shared__ float gs[256];
  gs[threadIdx.x] = key2f(A.gkeys[seg*256+threadIdx.x]);
  __syncthreads();
  const float* wrow = A.W3 + (size_t)cout*512;
  float s=0.f;
  #pragma unroll 8
  for (int k=0;k<256;k++) s = fmaf(wrow[k], gs[k], s);
  A.cseg[seg*512+cout]=s;
}

// ---------------- L3: weights LDS-resident, acts streamed as global B-frags ----------------
// 1024 blocks x 512 thr. Block = 256 couts (cgrp) x 256 pts (4 tiles). Wave (mq,tq):
// 128 couts x 64-pt tile, acc 32 f32x4 (forced resident). One barrier total.
__global__ __launch_bounds__(512,2) void k_l3(Args A){
  __shared__ unsigned short wlds[8*4*256*8];   // 128 KB [ks*4+kg][256 crel][8], 4096 B/slice
  __shared__ int offs_s[NSEG+1];
  int bid=blockIdx.x; int xcd=bid&7; int j=bid>>3;
  int cgrp=j&1, ptgrp=xcd*64+(j>>1);
  int tid=threadIdx.x, lane=tid&63, wv=tid>>6, quad=lane>>4, l16=lane&15;
  int mq=wv&1, tq=wv>>1;
  for (int i=wv*16;i<wv*16+16;++i){
    int slice=i>>2, q=i&3;
    const char* src=(const char*)(A.w3p + (size_t)slice*4096 + cgrp*2048 + q*512);
    gl16(src + lane*16, (char*)wlds + slice*4096 + q*1024);
  }
  if (tid<=NSEG) offs_s[tid]=A.offs[tid];
  __syncthreads();
  int tg = ptgrp*4 + tq, pt0 = tg*64;
  int sBeg=0; while (pt0 >= offs_s[sBeg+1]) sBeg++;
  int sEnd=sBeg; while (pt0+63 >= offs_s[sEnd+1]) sEnd++;
  bool uni=(sBeg==sEnd);
  int segl[4];
  if (!uni){
    #pragma unroll
    for (int nt=0;nt<4;++nt){ int gp=pt0+nt*16+l16, s=sBeg; while (gp>=offs_s[s+1]) s++; segl[nt]=s; }
  }
  f32x4 acc[8][4];
  for (int a=0;a<8;a++)
    for (int b=0;b<4;b++)
      acc[a][b]=(f32x4){0.f,0.f,0.f,0.f};
  const unsigned short* bsrc = A.fbufp + (size_t)tg*16384;
  bf16x8 bb[2][4];
  #pragma unroll
  for (int nt=0;nt<4;++nt) bb[0][nt]=*(const bf16x8*)(bsrc + (size_t)((quad*64 + nt*16 + l16)*8));
  #pragma unroll
  for (int nt=0;nt<4;++nt) bb[1][nt]=*(const bf16x8*)(bsrc + (size_t)(((4+quad)*64 + nt*16 + l16)*8));
  #pragma unroll
  for (int ksl=0; ksl<8; ++ksl){
    bf16x8 afr[8];
    #pragma unroll
    for (int mt=0;mt<8;++mt) afr[mt]=*(bf16x8*)(&wlds[((ksl*4+quad)*256 + mq*128 + mt*16 + l16)*8]);
    #pragma unroll
    for (int mt=0;mt<8;++mt)
      #pragma unroll
      for (int nt=0;nt<4;++nt)
        acc[mt][nt]=__builtin_amdgcn_mfma_f32_16x16x32_bf16(afr[mt], bb[ksl&1][nt], acc[mt][nt], 0,0,0);
    if (ksl+2<8){
      #pragma unroll
      for (int nt=0;nt<4;++nt) bb[ksl&1][nt]=*(const bf16x8*)(bsrc + (size_t)((((ksl+2)*4+quad)*64 + nt*16 + l16)*8));
    }
  }
  #pragma unroll
  for (int mt=0;mt<8;++mt){
    int cout0=cgrp*256 + mq*128 + mt*16 + quad*4;
    int kg=cout0>>3, sub=cout0&7;
    float sa[4],sc[4],csr[4];
    #pragma unroll
    for (int r=0;r<4;++r){ sa[r]=A.a3[cout0+r]; sc[r]=A.c3[cout0+r]; }
    if (uni){
      #pragma unroll
      for (int r=0;r<4;++r) csr[r]=A.cseg[sBeg*512+cout0+r];
    }
    #pragma unroll
    for (int nt=0;nt<4;++nt){
      int ptl=nt*16+l16;
      unsigned short us[4];
      #pragma unroll
      for (int r=0;r<4;++r){
        float cv = uni? csr[r] : A.cseg[segl[nt]*512+cout0+r];
        float hv = fmaxf(fmaf(sa[r], acc[mt][nt][r]+cv, sc[r]), 0.f);
        us[r]=f2bf(hv);
      }
      uint2 pk;
      pk.x=(unsigned)us[0]|((unsigned)us[1]<<16);
      pk.y=(unsigned)us[2]|((unsigned)us[3]<<16);
      *(uint2*)&A.h3p[(size_t)tg*32768 + (size_t)((kg*64+ptl)*8+sub)] = pk;
    }
  }
}

// ---------------- L4: weights LDS-resident, acts streamed, fused segmax ----------------
// 2048 blocks x 512 thr. Block = 128 couts (cgrp) x 512 pts (8 waves x 64-pt tile).
// XCD swizzle: 8 cgrps of one pt-range co-resident on one XCD -> act re-reads hit L2.
__global__ __launch_bounds__(512,2) void k_l4(Args A){
  __shared__ unsigned short wlds[16*4*128*8];  // 128 KB [ks*4+kg][128 crel][8], 2048 B/slice
  __shared__ int offs_s[NSEG+1];
  int bid=blockIdx.x; int xcd=bid&7; int j=bid>>3;
  int cgrp=j&7, ptgrp=xcd*32+(j>>3);
  int tid=threadIdx.x, lane=tid&63, wv=tid>>6, quad=lane>>4, l16=lane&15;
  for (int i=wv*16;i<wv*16+16;++i){
    int slice=i>>1, half=i&1;
    const char* src=(const char*)(A.w4p + (size_t)slice*8192 + cgrp*1024 + half*512);
    gl16(src + lane*16, (char*)wlds + slice*2048 + half*1024);
  }
  if (tid<=NSEG) offs_s[tid]=A.offs[tid];
  __syncthreads();
  int tg = ptgrp*8 + wv, pt0 = tg*64;
  int sBeg=0; while (pt0 >= offs_s[sBeg+1]) sBeg++;
  int sEnd=sBeg; while (pt0+63 >= offs_s[sEnd+1]) sEnd++;
  bool uni=(sBeg==sEnd);
  int segl[4];
  if (!uni){
    #pragma unroll
    for (int nt=0;nt<4;++nt){ int gp=pt0+nt*16+l16, s=sBeg; while (gp>=offs_s[s+1]) s++; segl[nt]=s; }
  }
  f32x4 acc[8][4];
  for (int a=0;a<8;a++)
    for (int b=0;b<4;b++)
      acc[a][b]=(f32x4){0.f,0.f,0.f,0.f};
  const unsigned short* bsrc = A.h3p + (size_t)tg*32768;
  bf16x8 bb[2][4];
  #pragma unroll
  for (int nt=0;nt<4;++nt) bb[0][nt]=*(const bf16x8*)(bsrc + (size_t)((quad*64 + nt*16 + l16)*8));
  #pragma unroll
  for (int nt=0;nt<4;++nt) bb[1][nt]=*(const bf16x8*)(bsrc + (size_t)(((4+quad)*64 + nt*16 + l16)*8));
  #pragma unroll
  for (int ksl=0; ksl<16; ++ksl){
    bf16x8 afr[8];
    #pragma unroll
    for (int mt=0;mt<8;++mt) afr[mt]=*(bf16x8*)(&wlds[((ksl*4+quad)*128 + mt*16 + l16)*8]);
    #pragma unroll
    for (int mt=0;mt<8;++mt)
      #pragma unroll
      for (int nt=0;nt<4;++nt)
        acc[mt][nt]=__builtin_amdgcn_mfma_f32_16x16x32_bf16(afr[mt], bb[ksl&1][nt], acc[mt][nt], 0,0,0);
    if (ksl+2<16){
      #pragma unroll
      for (int nt=0;nt<4;++nt) bb[ksl&1][nt]=*(const bf16x8*)(bsrc + (size_t)((((ksl+2)*4+quad)*64 + nt*16 + l16)*8));
    }
  }
  #pragma unroll
  for (int mt=0;mt<8;++mt){
    int cout0=cgrp*128 + mt*16 + quad*4;
    #pragma unroll
    for (int r=0;r<4;++r){
      int cout=cout0+r;
      float sa=A.a4[cout], sc=A.c4[cout];
      float mv=-3.4e38f;
      #pragma unroll
      for (int nt=0;nt<4;++nt){
        float fv=fmaf(sa, acc[mt][nt][r], sc);
        if (uni) mv=fmaxf(mv,fv);
        else atomicMax(&A.vkeys[segl[nt]*1024+cout], f2key(fv));
      }
      if (uni){
        #pragma unroll
        for (int off=8;off>=1;off>>=1) mv=fmaxf(mv, __shfl_xor(mv,off));
        if (l16==0) atomicMax(&A.vkeys[sBeg*1024+cout], f2key(mv));
      }
    }
  }
}

// ---------------- decode ----------------
__global__ void k_final(Args A){
  int i=blockIdx.x*256+threadIdx.x;
  if (i<NSEG*1024) A.out[i]=key2f(A.vkeys[i]);
}

extern "C" void kernel_launch(void* const* d_in, const int* in_sizes, int n_in,
                              void* d_out, int out_size, void* d_ws, size_t ws_size,
                              hipStream_t stream){
  Args A;
  A.x  =(const float*)d_in[0];  A.npts=(const int*)d_in[1];
  A.W1 =(const float*)d_in[2];  A.b1 =(const float*)d_in[3];
  A.g1 =(const float*)d_in[4];  A.be1=(const float*)d_in[5];
  A.m1 =(const float*)d_in[6];  A.v1 =(const float*)d_in[7];
  A.W2 =(const float*)d_in[8];  A.b2 =(const float*)d_in[9];
  A.g2 =(const float*)d_in[10]; A.be2=(const float*)d_in[11];
  A.m2 =(const float*)d_in[12]; A.v2 =(const float*)d_in[13];
  A.W3 =(const float*)d_in[14]; A.b3 =(const float*)d_in[15];
  A.g3 =(const float*)d_in[16]; A.be3=(const float*)d_in[17];
  A.m3 =(const float*)d_in[18]; A.v3 =(const float*)d_in[19];
  A.W4 =(const float*)d_in[20]; A.b4 =(const float*)d_in[21];
  A.g4 =(const float*)d_in[22]; A.be4=(const float*)d_in[23];
  A.m4 =(const float*)d_in[24]; A.v4 =(const float*)d_in[25];

  char* w=(char*)d_ws;
  auto alloc=[&](size_t b)->void*{ void* p=(void*)w; w += (b+255)&~(size_t)255; return p; };
  A.offs =(int*)alloc((NSEG+1)*4);
  A.a1=(float*)alloc(128*4);  A.c1=(float*)alloc(128*4);
  A.a2=(float*)alloc(256*4);  A.c2=(float*)alloc(256*4);
  A.a3=(float*)alloc(512*4);  A.c3=(float*)alloc(512*4);
  A.a4=(float*)alloc(1024*4); A.c4=(float*)alloc(1024*4);
  A.gkeys=(unsigned int*)alloc(NSEG*256*4);
  A.vkeys=(unsigned int*)alloc(NSEG*1024*4);
  A.cseg =(float*)alloc(NSEG*512*4);
  A.w2b=(unsigned short*)alloc(256*128*2);
  A.w3p=(unsigned short*)alloc(131072*2);
  A.w4p=(unsigned short*)alloc(524288*2);
  A.fbufp=(unsigned short*)alloc((size_t)2048*16384*2);  // 64 MB
  A.h3p  =(unsigned short*)alloc((size_t)2048*32768*2);  // 128 MB
  A.out=(float*)d_out;

  k_setup<<<dim3(1),dim3(256),0,stream>>>(A);
  k_conv <<<dim3(2688),dim3(256),0,stream>>>(A);
  k_l12  <<<dim3(NTOT/64),dim3(256),0,stream>>>(A);
  k_cseg <<<dim3(32),dim3(256),0,stream>>>(A);
  k_l3   <<<dim3(1024),dim3(512),0,stream>>>(A);
  k_l4   <<<dim3(2048),dim3(512),0,stream>>>(A);
  k_final<<<dim3(64),dim3(256),0,stream>>>(A);
}